// Round 3
// baseline (1036.351 us; speedup 1.0000x reference)
//
#include <hip/hip_runtime.h>
#include <hip/hip_bf16.h>

#define NIN 32
#define NHID 128
#define NOUT 16
#define NIN1 160   // NIN+NHID = 160 feature records, K = 160*8 = 1280
#define SEQT 512
#define NB 256

typedef __attribute__((ext_vector_type(8))) short s16x8;   // 8 bf16 (4 VGPRs) - MFMA A/B frag
typedef __attribute__((ext_vector_type(4))) float f32x4;   // MFMA C/D frag

// manual RNE f32->bf16 (inputs are finite/sane here)
__device__ __forceinline__ unsigned int f2bfbits(float f) {
    unsigned int u = __float_as_uint(f);
    return (u + 0x7fffu + ((u >> 16) & 1u)) >> 16;
}
__device__ __forceinline__ unsigned int packbf(float lo, float hi) {
    return f2bfbits(lo) | (f2bfbits(hi) << 16);
}

// Knots: t_m = -8.8 + 1.6*m (G=5, K=3, range [-4,4]); uniform -> closed-form
// cubic basis (verified PASS in round 1).
__device__ __forceinline__ void spline_feat(float c, float* out4, int* jst) {
    const float t0 = -8.8f, inv_h = 0.625f;
    float u  = (c - t0) * inv_h;
    float uf = floorf(u);
    int   m0 = (int)uf;
    bool valid = (m0 >= 0) && (m0 <= 10);
    float f   = u - uf;
    float omf = 1.0f - f;
    float f2 = f * f, f3 = f2 * f;
    float omf3 = omf * omf * omf;
    const float c6 = 0.16666667f;
    float v0 = omf3 * c6;
    float v1 = __builtin_fmaf(3.0f, f3, __builtin_fmaf(-6.0f, f2, 4.0f)) * c6;
    float v2 = __builtin_fmaf(-3.0f, f3, __builtin_fmaf(3.0f, f + f2, 1.0f)) * c6;
    float v3 = f3 * c6;
    float v[4] = {v0, v1, v2, v3};
    int jb = m0 - 3;
    int js = jb < 0 ? 0 : (jb > 4 ? 4 : jb);
    int sh = js - jb;
    #pragma unroll
    for (int r = 0; r < 4; ++r) {
        int rs = r + sh;
        out4[r] = (valid && rs >= 0 && rs <= 3) ? v[rs] : 0.f;
    }
    *jst = js;
}

__device__ __forceinline__ float fsilu(float c) {
    return c * __builtin_amdgcn_rcpf(1.f + __expf(-c));
}

// ---- X-macro lists ----
#define R20(X) X(0) X(1) X(2) X(3) X(4) X(5) X(6) X(7) X(8) X(9) \
               X(10) X(11) X(12) X(13) X(14) X(15) X(16) X(17) X(18) X(19)
#define O8(X) X(0) X(1) X(2) X(3) X(4) X(5) X(6) X(7)
#define K5(X) X(0) X(1) X(2) X(3) X(4)

__attribute__((amdgpu_waves_per_eu(2, 2)))   // 2 waves/EU -> 256-reg budget
__global__ void __launch_bounds__(512)
kan_seq(const float* __restrict__ x,
        const float* __restrict__ coef1,
        const float* __restrict__ sb1,
        const float* __restrict__ sp1,
        const float* __restrict__ coef2,
        const float* __restrict__ sb2,
        const float* __restrict__ sp2,
        float* __restrict__ out)
{
    __shared__ __align__(16) unsigned int Fb[NIN1][4];  // 8 bf16 basis per record (= MFMA B-frag rows)
    __shared__ float Fsil[NIN1];                        // f32 silu per record
    __shared__ __align__(16) float red[8][NHID];        // per-wave MFMA K-partials
    __shared__ float redb[4][NHID];                     // per-seg base-term partials
    __shared__ float Hf[NHID][9];                       // epilogue h-features

    const int tid  = threadIdx.x;
    const int b    = blockIdx.x;      // one batch row per block
    const int lane = tid & 63;
    const int w    = tid >> 6;        // wave 0..7: owns K-tiles w*5 .. w*5+4
    const int o    = tid & 127;
    const int seg  = tid >> 7;        // 0..3 for the VALU base dot
    const int arow = lane & 15;       // o-within-tile (A row / D col)
    const int agrp = lane >> 4;       // record-within-K-tile (0..3)

    // ---- one-time: A-fragments (weights) -> 40 NAMED uint4 regs, sp1 folded ----
    // A-frag for (kk, ot): lane holds coef1[rec][o][0..8)*sp1[rec][o] packed bf16,
    // rec = kk*4 + (lane>>4), o = ot*16 + (lane&15). Matches mfma_16x16x32 A layout.
#define DECLW(k) uint4 wf##k##_0, wf##k##_1, wf##k##_2, wf##k##_3, \
                       wf##k##_4, wf##k##_5, wf##k##_6, wf##k##_7;
    K5(DECLW)
#undef DECLW

#define INITW1(k,t) { \
    int rec = (w * 5 + (k)) * 4 + agrp; \
    int oo  = (t) * 16 + arow; \
    const float4* cp = (const float4*)(coef1 + (size_t)(rec * NHID + oo) * 8); \
    float sp = sp1[rec * NHID + oo]; \
    float4 c0 = cp[0], c1 = cp[1]; \
    wf##k##_##t = make_uint4(packbf(sp * c0.x, sp * c0.y), packbf(sp * c0.z, sp * c0.w), \
                             packbf(sp * c1.x, sp * c1.y), packbf(sp * c1.z, sp * c1.w)); }
#define INITWK(k) INITW1(k,0) INITW1(k,1) INITW1(k,2) INITW1(k,3) \
                  INITW1(k,4) INITW1(k,5) INITW1(k,6) INITW1(k,7)
    K5(INITWK)
#undef INITWK
#undef INITW1

    // base-term weights: 20 bf16 pairs per thread (seg's 40 i's)
#define DECLSB(p) unsigned int sbp##p;
    R20(DECLSB)
#undef DECLSB
#define INITSB(p) { int iA = seg * 40 + 2 * (p); \
    sbp##p = packbf(sb1[iA * NHID + o], sb1[(iA + 1) * NHID + o]); }
    R20(INITSB)
#undef INITSB

    // h0 = 0
    ((float*)red)[tid] = 0.f;
    ((float*)red)[tid + 512] = 0.f;
    ((float*)redb)[tid] = 0.f;
    float xv = (tid < NIN) ? x[(size_t)b * SEQT * NIN + tid] : 0.f;
    __syncthreads();

    const int fbase = w * 20 + agrp;   // Fb row of this lane's record in K-tile 0

    for (int t = 0; t < SEQT; ++t) {
        // ---- phase 1: features for all 160 inputs (160 threads) ----
        if (tid < NIN1) {
            float c;
            if (tid < NIN) c = xv;
            else {
                int hi = tid - NIN;
                c = ((red[0][hi] + red[1][hi]) + (red[2][hi] + red[3][hi]))
                  + ((red[4][hi] + red[5][hi]) + (red[6][hi] + red[7][hi]))
                  + ((redb[0][hi] + redb[1][hi]) + (redb[2][hi] + redb[3][hi]));
            }
            Fsil[tid] = fsilu(c);
            float b4[4]; int js;
            spline_feat(c, b4, &js);
            float e[8];
            #pragma unroll
            for (int k = 0; k < 8; ++k) {
                int d = k - js;
                e[k] = (d >= 0 && d < 4) ? b4[d] : 0.f;
            }
            uint4 pk;
            pk.x = packbf(e[0], e[1]); pk.y = packbf(e[2], e[3]);
            pk.z = packbf(e[4], e[5]); pk.w = packbf(e[6], e[7]);
            *(uint4*)&Fb[tid][0] = pk;
        }
        if (tid < NIN) {   // prefetch next timestep's x
            int tn = (t + 1 < SEQT) ? (t + 1) : t;
            xv = x[((size_t)b * SEQT + tn) * NIN + tid];
        }
        __syncthreads();

        // ---- phase 2a: first two B-frag reads (16-lane broadcast rows) ----
        uint4 bq0 = *(const uint4*)&Fb[fbase][0];
        uint4 bq1 = *(const uint4*)&Fb[fbase + 4][0];

        // ---- phase 2b: base term on VALU (f32 silu x bf16 sb1) — covers the
        //      LDS latency of bq0/bq1; co-issues with MFMA afterwards ----
        float vsil = Fsil[seg * 40 + (lane < 40 ? lane : 0)];
        float bc0 = 0.f, bc1 = 0.f;
#define DOTB(p) { \
        float sb_lo = __uint_as_float(sbp##p << 16); \
        float sb_hi = __uint_as_float(sbp##p & 0xffff0000u); \
        float slA = __int_as_float(__builtin_amdgcn_readlane(__float_as_int(vsil), 2 * (p))); \
        float slB = __int_as_float(__builtin_amdgcn_readlane(__float_as_int(vsil), 2 * (p) + 1)); \
        bc0 = __builtin_fmaf(slA, sb_lo, bc0); \
        bc1 = __builtin_fmaf(slB, sb_hi, bc1); }
        R20(DOTB)
#undef DOTB
        redb[seg][o] = bc0 + bc1;

        // ---- phase 2c: 40 MFMAs (5 K-tiles x 8 o-tiles), weights resident,
        //      2-deep staged B reads (live set = 2 uint4, peak VGPR trimmed) ----
#define DECLAC(t) f32x4 ac##t = {0.f, 0.f, 0.f, 0.f};
        O8(DECLAC)
#undef DECLAC
#define MMROW(k, bqv) { s16x8 bb_ = __builtin_bit_cast(s16x8, bqv); \
        ac0 = __builtin_amdgcn_mfma_f32_16x16x32_bf16(__builtin_bit_cast(s16x8, wf##k##_0), bb_, ac0, 0, 0, 0); \
        ac1 = __builtin_amdgcn_mfma_f32_16x16x32_bf16(__builtin_bit_cast(s16x8, wf##k##_1), bb_, ac1, 0, 0, 0); \
        ac2 = __builtin_amdgcn_mfma_f32_16x16x32_bf16(__builtin_bit_cast(s16x8, wf##k##_2), bb_, ac2, 0, 0, 0); \
        ac3 = __builtin_amdgcn_mfma_f32_16x16x32_bf16(__builtin_bit_cast(s16x8, wf##k##_3), bb_, ac3, 0, 0, 0); \
        ac4 = __builtin_amdgcn_mfma_f32_16x16x32_bf16(__builtin_bit_cast(s16x8, wf##k##_4), bb_, ac4, 0, 0, 0); \
        ac5 = __builtin_amdgcn_mfma_f32_16x16x32_bf16(__builtin_bit_cast(s16x8, wf##k##_5), bb_, ac5, 0, 0, 0); \
        ac6 = __builtin_amdgcn_mfma_f32_16x16x32_bf16(__builtin_bit_cast(s16x8, wf##k##_6), bb_, ac6, 0, 0, 0); \
        ac7 = __builtin_amdgcn_mfma_f32_16x16x32_bf16(__builtin_bit_cast(s16x8, wf##k##_7), bb_, ac7, 0, 0, 0); }
        MMROW(0, bq0)  uint4 bq2 = *(const uint4*)&Fb[fbase + 8][0];
        MMROW(1, bq1)  uint4 bq3 = *(const uint4*)&Fb[fbase + 12][0];
        MMROW(2, bq2)  uint4 bq4 = *(const uint4*)&Fb[fbase + 16][0];
        MMROW(3, bq3)
        MMROW(4, bq4)
#undef MMROW

        // ---- write this wave's 128 K-partial h values (D cols identical; lane
        //      group (lane&15)==ot stores rows (lane>>4)*4..+3 of tile ot) ----
#define WRR(t) if ((lane & 15) == (t)) \
            *(f32x4*)&red[w][(t) * 16 + (agrp << 2)] = ac##t;
        O8(WRR)
#undef WRR
        __syncthreads();
    }

    // ---- layer 2 on final h only (fp32; verified earlier) ----
    if (tid < NHID) {
        float c = ((red[0][tid] + red[1][tid]) + (red[2][tid] + red[3][tid]))
                + ((red[4][tid] + red[5][tid]) + (red[6][tid] + red[7][tid]))
                + ((redb[0][tid] + redb[1][tid]) + (redb[2][tid] + redb[3][tid]));
        float sil = fsilu(c);
        float b4[4]; int js;
        spline_feat(c, b4, &js);
        #pragma unroll
        for (int k = 0; k < 8; ++k) {
            int d = k - js;
            Hf[tid][k] = (d >= 0 && d < 4) ? b4[d] : 0.f;
        }
        Hf[tid][8] = sil;
    }
    __syncthreads();
    if (tid < 128) {
        int o2 = tid & 15, isg = tid >> 4;     // 8 i-groups of 16
        float acc = 0.f;
        for (int q = 0; q < 16; ++q) {
            int i = isg * 16 + q;
            const float* c2 = coef2 + (size_t)(i * NOUT + o2) * 8;
            float s = 0.f;
            #pragma unroll
            for (int k = 0; k < 8; ++k) s += Hf[i][k] * c2[k];
            acc += Hf[i][8] * sb2[i * NOUT + o2] + sp2[i * NOUT + o2] * s;
        }
        ((float*)red)[isg * 16 + o2] = acc;
    }
    __syncthreads();
    if (tid < NOUT) {
        float a = 0.f;
        #pragma unroll
        for (int g = 0; g < 8; ++g) a += ((float*)red)[g * 16 + tid];
        out[(size_t)b * NOUT + tid] = a;
    }
}

extern "C" void kernel_launch(void* const* d_in, const int* in_sizes, int n_in,
                              void* d_out, int out_size, void* d_ws, size_t ws_size,
                              hipStream_t stream) {
    kan_seq<<<NB, 512, 0, stream>>>(
        (const float*)d_in[0], (const float*)d_in[1], (const float*)d_in[2],
        (const float*)d_in[3], (const float*)d_in[4], (const float*)d_in[5],
        (const float*)d_in[6], (float*)d_out);
}